// Round 1
// baseline (1147.738 us; speedup 1.0000x reference)
//
#include <hip/hip_runtime.h>
#include <cstdint>
#include <cstddef>

// Graph U-Net (no pooling), N=8192, D=256, L=3.
// Strategy: g is ~1.5% dense after symmetrization (~127 avg degree).
// Build a fixed-stride ushort adjacency list once (one 256 MB pass over g),
// then 7x (SpMM gather + fused GEMM w/ bias+relu+skip+dinv-prescale).
// All fp32 for exact-ish accuracy this round.

#define GN 8192
#define GD 256
#define CAP 320   // max degree capacity; Binomial(8191, .0155) max ~175, 320 is safe

// ---------------------------------------------------------------------------
// Kernel 1: build adjacency lists + dinv. One block per row.
// cnt[i] = #nonzeros in row i of g; dinv[i] = rsqrt(cnt+1)  (self-loop in ref)
// col[i*CAP + t] = column indices of nonzeros (order irrelevant for the sum).
__global__ __launch_bounds__(256) void k_build(const float* __restrict__ g,
                                               unsigned short* __restrict__ col,
                                               int* __restrict__ cnt,
                                               float* __restrict__ dinv)
{
    __shared__ int s_cnt;
    const int i = blockIdx.x;
    const int tid = threadIdx.x;
    if (tid == 0) s_cnt = 0;
    __syncthreads();
    const float4* grow = (const float4*)(g + (size_t)i * GN);
    unsigned short* crow = col + (size_t)i * CAP;
    for (int j4 = tid; j4 < GN / 4; j4 += 256) {
        float4 v = grow[j4];
        int j = j4 * 4;
        if (v.x != 0.0f) { int p = atomicAdd(&s_cnt, 1); if (p < CAP) crow[p] = (unsigned short)(j + 0); }
        if (v.y != 0.0f) { int p = atomicAdd(&s_cnt, 1); if (p < CAP) crow[p] = (unsigned short)(j + 1); }
        if (v.z != 0.0f) { int p = atomicAdd(&s_cnt, 1); if (p < CAP) crow[p] = (unsigned short)(j + 2); }
        if (v.w != 0.0f) { int p = atomicAdd(&s_cnt, 1); if (p < CAP) crow[p] = (unsigned short)(j + 3); }
    }
    __syncthreads();
    if (tid == 0) {
        int n = s_cnt; if (n > CAP) n = CAP;
        cnt[i] = n;
        dinv[i] = rsqrtf((float)s_cnt + 1.0f);
    }
}

// ---------------------------------------------------------------------------
// Kernel 2: hs = dinv[:,None] * h   (initial pre-scale)
__global__ __launch_bounds__(256) void k_scale(const float* __restrict__ h,
                                               const float* __restrict__ dinv,
                                               float* __restrict__ hs)
{
    int idx = blockIdx.x * 256 + threadIdx.x;      // float4 index
    float4 v = ((const float4*)h)[idx];
    int row = idx / (GD / 4);
    float dv = dinv[row];
    v.x *= dv; v.y *= dv; v.z *= dv; v.w *= dv;
    ((float4*)hs)[idx] = v;
}

// ---------------------------------------------------------------------------
// Kernel 3: SpMM aggregation. y[i,:] = dinv[i] * (hs[i,:] + sum_cols hs[c,:])
// One block (256 threads) per row; thread t owns column t. Gathers are
// wave-coalesced 256B segments of contiguous hs rows.
__global__ __launch_bounds__(256) void k_spmm(const float* __restrict__ hs,
                                              const unsigned short* __restrict__ col,
                                              const int* __restrict__ cnt,
                                              const float* __restrict__ dinv,
                                              float* __restrict__ y)
{
    __shared__ unsigned short s_cols[CAP];
    const int i = blockIdx.x;
    const int tid = threadIdx.x;
    const int n = cnt[i];
    for (int t = tid; t < n; t += 256) s_cols[t] = col[(size_t)i * CAP + t];
    __syncthreads();

    float acc = hs[i * GD + tid];   // self-loop (+I term)
    int t = 0;
    for (; t + 8 <= n; t += 8) {
        int c0 = s_cols[t + 0], c1 = s_cols[t + 1], c2 = s_cols[t + 2], c3 = s_cols[t + 3];
        int c4 = s_cols[t + 4], c5 = s_cols[t + 5], c6 = s_cols[t + 6], c7 = s_cols[t + 7];
        float v0 = hs[c0 * GD + tid], v1 = hs[c1 * GD + tid];
        float v2 = hs[c2 * GD + tid], v3 = hs[c3 * GD + tid];
        float v4 = hs[c4 * GD + tid], v5 = hs[c5 * GD + tid];
        float v6 = hs[c6 * GD + tid], v7 = hs[c7 * GD + tid];
        acc += ((v0 + v1) + (v2 + v3)) + ((v4 + v5) + (v6 + v7));
    }
    for (; t < n; ++t) acc += hs[s_cols[t] * GD + tid];
    y[i * GD + tid] = dinv[i] * acc;
}

// ---------------------------------------------------------------------------
// Kernel 4: fused linear layer.  out = relu(Y @ W^T + b), plus epilogues:
//   h_out[idx]  = v                         (store layer output if needed)
//   hs_out[idx] = dinv[m] * (v + skip[idx]) (pre-scaled input for next SpMM)
//   sum_out[idx]= v + add_src[idx]          (final h + org_h output)
// Tiled fp32: 64x64 block tile, BK=32, 4x4 per-thread register tile.
__global__ __launch_bounds__(256) void k_gemm(const float* __restrict__ Y,
                                              const float* __restrict__ W,
                                              const float* __restrict__ bias,
                                              const float* __restrict__ dinv,
                                              const float* __restrict__ skip,
                                              float* __restrict__ h_out,
                                              float* __restrict__ hs_out,
                                              float* __restrict__ sum_out,
                                              const float* __restrict__ add_src)
{
    const int BM = 64, BN = 64, BK = 32;
    __shared__ float sY[BM][BK + 1];
    __shared__ float sW[BN][BK + 1];
    const int by = blockIdx.x;   // 0..127 row tiles
    const int bx = blockIdx.y;   // 0..3   col tiles
    const int tid = threadIdx.x;
    const int tx = tid & 15, ty = tid >> 4;
    const int row0 = by * BM, col0 = bx * BN;
    const int lrow = tid >> 3;        // 0..31
    const int lk = (tid & 7) * 4;     // 0,4,...,28

    float acc[4][4] = {};

    for (int k0 = 0; k0 < GD; k0 += BK) {
        float4 ya = *(const float4*)&Y[(size_t)(row0 + lrow) * GD + k0 + lk];
        float4 yb = *(const float4*)&Y[(size_t)(row0 + lrow + 32) * GD + k0 + lk];
        float4 wa = *(const float4*)&W[(size_t)(col0 + lrow) * GD + k0 + lk];
        float4 wb = *(const float4*)&W[(size_t)(col0 + lrow + 32) * GD + k0 + lk];
        __syncthreads();
        sY[lrow][lk + 0] = ya.x; sY[lrow][lk + 1] = ya.y; sY[lrow][lk + 2] = ya.z; sY[lrow][lk + 3] = ya.w;
        sY[lrow + 32][lk + 0] = yb.x; sY[lrow + 32][lk + 1] = yb.y; sY[lrow + 32][lk + 2] = yb.z; sY[lrow + 32][lk + 3] = yb.w;
        sW[lrow][lk + 0] = wa.x; sW[lrow][lk + 1] = wa.y; sW[lrow][lk + 2] = wa.z; sW[lrow][lk + 3] = wa.w;
        sW[lrow + 32][lk + 0] = wb.x; sW[lrow + 32][lk + 1] = wb.y; sW[lrow + 32][lk + 2] = wb.z; sW[lrow + 32][lk + 3] = wb.w;
        __syncthreads();
#pragma unroll
        for (int k = 0; k < BK; ++k) {
            float a0 = sY[ty * 4 + 0][k], a1 = sY[ty * 4 + 1][k];
            float a2 = sY[ty * 4 + 2][k], a3 = sY[ty * 4 + 3][k];
            float b0 = sW[tx * 4 + 0][k], b1 = sW[tx * 4 + 1][k];
            float b2 = sW[tx * 4 + 2][k], b3 = sW[tx * 4 + 3][k];
            acc[0][0] += a0 * b0; acc[0][1] += a0 * b1; acc[0][2] += a0 * b2; acc[0][3] += a0 * b3;
            acc[1][0] += a1 * b0; acc[1][1] += a1 * b1; acc[1][2] += a1 * b2; acc[1][3] += a1 * b3;
            acc[2][0] += a2 * b0; acc[2][1] += a2 * b1; acc[2][2] += a2 * b2; acc[2][3] += a2 * b3;
            acc[3][0] += a3 * b0; acc[3][1] += a3 * b1; acc[3][2] += a3 * b2; acc[3][3] += a3 * b3;
        }
    }

#pragma unroll
    for (int ii = 0; ii < 4; ++ii) {
        int m = row0 + ty * 4 + ii;
        float dvm = dinv[m];
#pragma unroll
        for (int jj = 0; jj < 4; ++jj) {
            int n = col0 + tx * 4 + jj;
            float v = acc[ii][jj] + bias[n];
            v = fmaxf(v, 0.0f);
            size_t idx = (size_t)m * GD + n;
            if (h_out)  h_out[idx] = v;
            if (hs_out) {
                float s = skip ? skip[idx] : 0.0f;
                hs_out[idx] = dvm * (v + s);
            }
            if (sum_out) sum_out[idx] = v + add_src[idx];
        }
    }
}

// ---------------------------------------------------------------------------
extern "C" void kernel_launch(void* const* d_in, const int* in_sizes, int n_in,
                              void* d_out, int out_size, void* d_ws, size_t ws_size,
                              hipStream_t stream)
{
    const float* g  = (const float*)d_in[0];
    const float* h  = (const float*)d_in[1];
    const float* Wd = (const float*)d_in[2];
    const float* bd = (const float*)d_in[3];
    const float* Wb = (const float*)d_in[4];
    const float* bb = (const float*)d_in[5];
    const float* Wu = (const float*)d_in[6];
    const float* bu = (const float*)d_in[7];
    float* out = (float*)d_out;

    char* ws = (char*)d_ws;
    float*          dinv = (float*)ws;                               // 32 KB
    int*            cnt  = (int*)(ws + 32 * 1024);                   // 32 KB
    unsigned short* col  = (unsigned short*)(ws + 64 * 1024);        // 8192*CAP*2 = 5.24 MB
    size_t off = 64 * 1024 + (size_t)GN * CAP * sizeof(unsigned short);
    float* hs    = (float*)(ws + off);            // 8 MB
    float* yb    = hs + (size_t)GN * GD;          // 8 MB
    float* dbuf1 = yb + (size_t)GN * GD;          // 8 MB  (down_outs[0])
    float* dbuf2 = dbuf1 + (size_t)GN * GD;       // 8 MB  (down_outs[1])
    float* dbuf3 = dbuf2 + (size_t)GN * GD;       // 8 MB  (down_outs[2])
    (void)ws_size; (void)in_sizes; (void)n_in; (void)out_size;

    const size_t ND = (size_t)GN * GD;
    dim3 ggrid(GN / 64, GD / 64);

    k_build<<<GN, 256, 0, stream>>>(g, col, cnt, dinv);
    k_scale<<<GN * GD / 4 / 256, 256, 0, stream>>>(h, dinv, hs);

    // down 0..2: h_out -> dbuf, hs_out = dinv*h_next
    k_spmm<<<GN, 256, 0, stream>>>(hs, col, cnt, dinv, yb);
    k_gemm<<<ggrid, 256, 0, stream>>>(yb, Wd + 0 * GD * GD, bd + 0 * GD, dinv, nullptr, dbuf1, hs, nullptr, nullptr);
    k_spmm<<<GN, 256, 0, stream>>>(hs, col, cnt, dinv, yb);
    k_gemm<<<ggrid, 256, 0, stream>>>(yb, Wd + 1 * GD * GD, bd + 1 * GD, dinv, nullptr, dbuf2, hs, nullptr, nullptr);
    k_spmm<<<GN, 256, 0, stream>>>(hs, col, cnt, dinv, yb);
    k_gemm<<<ggrid, 256, 0, stream>>>(yb, Wd + 2 * GD * GD, bd + 2 * GD, dinv, nullptr, dbuf3, hs, nullptr, nullptr);

    // bottom: h4 only feeds next hs with skip = down_outs[2]
    k_spmm<<<GN, 256, 0, stream>>>(hs, col, cnt, dinv, yb);
    k_gemm<<<ggrid, 256, 0, stream>>>(yb, Wb, bb, dinv, dbuf3, nullptr, hs, nullptr, nullptr);

    // up 0: out[0] = h5; next hs = dinv*(h5 + down_outs[1])
    k_spmm<<<GN, 256, 0, stream>>>(hs, col, cnt, dinv, yb);
    k_gemm<<<ggrid, 256, 0, stream>>>(yb, Wu + 0 * GD * GD, bu + 0 * GD, dinv, dbuf2, out + 0 * ND, hs, nullptr, nullptr);
    // up 1: out[1] = h6; next hs = dinv*(h6 + down_outs[0])
    k_spmm<<<GN, 256, 0, stream>>>(hs, col, cnt, dinv, yb);
    k_gemm<<<ggrid, 256, 0, stream>>>(yb, Wu + 1 * GD * GD, bu + 1 * GD, dinv, dbuf1, out + 1 * ND, hs, nullptr, nullptr);
    // up 2: out[2] = h7; out[3] = h7 + org_h
    k_spmm<<<GN, 256, 0, stream>>>(hs, col, cnt, dinv, yb);
    k_gemm<<<ggrid, 256, 0, stream>>>(yb, Wu + 2 * GD * GD, bu + 2 * GD, dinv, nullptr, out + 2 * ND, nullptr, out + 3 * ND, h);
}

// Round 2
// 926.626 us; speedup vs baseline: 1.2386x; 1.2386x over previous
//
#include <hip/hip_runtime.h>
#include <cstdint>
#include <cstddef>

// Graph U-Net (no pooling), N=8192, D=256, L=3.
// g is ~1.5% dense after symmetrization (~127 avg degree). Build a
// fixed-stride ushort adjacency list once, then 7x (SpMM gather + fused GEMM).
// R2: column-chunked SpMM — each (row, 64-col chunk) touches only a 2 MB
// cache-line footprint of hs, resident in each XCD's 4 MB L2 (was 8 MB ->
// L2 thrash -> L3-bound ~105 us/SpMM).

#define GN 8192
#define GD 256
#define CAP 320   // max degree capacity; Binomial(8191, .0155) max ~175, 320 is safe

// ---------------------------------------------------------------------------
// Kernel 1: build adjacency lists + dinv. One block per row.
__global__ __launch_bounds__(256) void k_build(const float* __restrict__ g,
                                               unsigned short* __restrict__ col,
                                               int* __restrict__ cnt,
                                               float* __restrict__ dinv)
{
    __shared__ int s_cnt;
    const int i = blockIdx.x;
    const int tid = threadIdx.x;
    if (tid == 0) s_cnt = 0;
    __syncthreads();
    const float4* grow = (const float4*)(g + (size_t)i * GN);
    unsigned short* crow = col + (size_t)i * CAP;
    for (int j4 = tid; j4 < GN / 4; j4 += 256) {
        float4 v = grow[j4];
        int j = j4 * 4;
        if (v.x != 0.0f) { int p = atomicAdd(&s_cnt, 1); if (p < CAP) crow[p] = (unsigned short)(j + 0); }
        if (v.y != 0.0f) { int p = atomicAdd(&s_cnt, 1); if (p < CAP) crow[p] = (unsigned short)(j + 1); }
        if (v.z != 0.0f) { int p = atomicAdd(&s_cnt, 1); if (p < CAP) crow[p] = (unsigned short)(j + 2); }
        if (v.w != 0.0f) { int p = atomicAdd(&s_cnt, 1); if (p < CAP) crow[p] = (unsigned short)(j + 3); }
    }
    __syncthreads();
    if (tid == 0) {
        int n = s_cnt; if (n > CAP) n = CAP;
        cnt[i] = n;
        dinv[i] = rsqrtf((float)s_cnt + 1.0f);
    }
}

// ---------------------------------------------------------------------------
// Kernel 2: hs = dinv[:,None] * h   (initial pre-scale)
__global__ __launch_bounds__(256) void k_scale(const float* __restrict__ h,
                                               const float* __restrict__ dinv,
                                               float* __restrict__ hs)
{
    int idx = blockIdx.x * 256 + threadIdx.x;      // float4 index
    float4 v = ((const float4*)h)[idx];
    int row = idx / (GD / 4);
    float dv = dinv[row];
    v.x *= dv; v.y *= dv; v.z *= dv; v.w *= dv;
    ((float4*)hs)[idx] = v;
}

// ---------------------------------------------------------------------------
// Kernel 3: column-chunked SpMM. y[i, c0+lc] = dinv[i]*(hs[i,c0+lc] + sum_n hs[n,c0+lc])
// Grid (GN/4, 4): 4 rows per block, one 64-column chunk per blockIdx.y.
// Each 64-lane group == one wave owns one row: its own s_cols slice, its own
// 256B-contiguous gathers, broadcast index reads -> NO barriers needed.
// Per-chunk touched footprint of hs = 8192 * 256B = 2 MB -> L2-resident.
__global__ __launch_bounds__(256) void k_spmm(const float* __restrict__ hs,
                                              const unsigned short* __restrict__ col,
                                              const int* __restrict__ cnt,
                                              const float* __restrict__ dinv,
                                              float* __restrict__ y)
{
    __shared__ unsigned short s_cols[4][CAP];
    const int lr = threadIdx.x >> 6;        // local row 0..3 (one wave each)
    const int lc = threadIdx.x & 63;        // column within chunk
    const int i  = blockIdx.x * 4 + lr;
    const int c  = blockIdx.y * 64 + lc;
    const int n  = cnt[i];
    unsigned short* sc = s_cols[lr];
    for (int t = lc; t < n; t += 64) sc[t] = col[(size_t)i * CAP + t];
    // wave-coherent: loads and uses are within the same wave; lgkmcnt/vmcnt
    // dependencies are handled by the compiler. No __syncthreads.

    float acc = hs[(size_t)i * GD + c];     // self-loop (+I term)
    int t = 0;
    for (; t + 8 <= n; t += 8) {
        int c0 = sc[t + 0], c1 = sc[t + 1], c2 = sc[t + 2], c3 = sc[t + 3];
        int c4 = sc[t + 4], c5 = sc[t + 5], c6 = sc[t + 6], c7 = sc[t + 7];
        float v0 = hs[(size_t)c0 * GD + c], v1 = hs[(size_t)c1 * GD + c];
        float v2 = hs[(size_t)c2 * GD + c], v3 = hs[(size_t)c3 * GD + c];
        float v4 = hs[(size_t)c4 * GD + c], v5 = hs[(size_t)c5 * GD + c];
        float v6 = hs[(size_t)c6 * GD + c], v7 = hs[(size_t)c7 * GD + c];
        acc += ((v0 + v1) + (v2 + v3)) + ((v4 + v5) + (v6 + v7));
    }
    for (; t < n; ++t) acc += hs[(size_t)sc[t] * GD + c];
    y[(size_t)i * GD + c] = dinv[i] * acc;
}

// ---------------------------------------------------------------------------
// Kernel 4: fused linear layer.  out = relu(Y @ W^T + b), plus epilogues:
//   h_out[idx]  = v                         (store layer output if needed)
//   hs_out[idx] = dinv[m] * (v + skip[idx]) (pre-scaled input for next SpMM)
//   sum_out[idx]= v + add_src[idx]          (final h + org_h output)
__global__ __launch_bounds__(256) void k_gemm(const float* __restrict__ Y,
                                              const float* __restrict__ W,
                                              const float* __restrict__ bias,
                                              const float* __restrict__ dinv,
                                              const float* __restrict__ skip,
                                              float* __restrict__ h_out,
                                              float* __restrict__ hs_out,
                                              float* __restrict__ sum_out,
                                              const float* __restrict__ add_src)
{
    const int BM = 64, BN = 64, BK = 32;
    __shared__ float sY[BM][BK + 1];
    __shared__ float sW[BN][BK + 1];
    const int by = blockIdx.x;   // 0..127 row tiles
    const int bx = blockIdx.y;   // 0..3   col tiles
    const int tid = threadIdx.x;
    const int tx = tid & 15, ty = tid >> 4;
    const int row0 = by * BM, col0 = bx * BN;
    const int lrow = tid >> 3;        // 0..31
    const int lk = (tid & 7) * 4;     // 0,4,...,28

    float acc[4][4] = {};

    for (int k0 = 0; k0 < GD; k0 += BK) {
        float4 ya = *(const float4*)&Y[(size_t)(row0 + lrow) * GD + k0 + lk];
        float4 yb = *(const float4*)&Y[(size_t)(row0 + lrow + 32) * GD + k0 + lk];
        float4 wa = *(const float4*)&W[(size_t)(col0 + lrow) * GD + k0 + lk];
        float4 wb = *(const float4*)&W[(size_t)(col0 + lrow + 32) * GD + k0 + lk];
        __syncthreads();
        sY[lrow][lk + 0] = ya.x; sY[lrow][lk + 1] = ya.y; sY[lrow][lk + 2] = ya.z; sY[lrow][lk + 3] = ya.w;
        sY[lrow + 32][lk + 0] = yb.x; sY[lrow + 32][lk + 1] = yb.y; sY[lrow + 32][lk + 2] = yb.z; sY[lrow + 32][lk + 3] = yb.w;
        sW[lrow][lk + 0] = wa.x; sW[lrow][lk + 1] = wa.y; sW[lrow][lk + 2] = wa.z; sW[lrow][lk + 3] = wa.w;
        sW[lrow + 32][lk + 0] = wb.x; sW[lrow + 32][lk + 1] = wb.y; sW[lrow + 32][lk + 2] = wb.z; sW[lrow + 32][lk + 3] = wb.w;
        __syncthreads();
#pragma unroll
        for (int k = 0; k < BK; ++k) {
            float a0 = sY[ty * 4 + 0][k], a1 = sY[ty * 4 + 1][k];
            float a2 = sY[ty * 4 + 2][k], a3 = sY[ty * 4 + 3][k];
            float b0 = sW[tx * 4 + 0][k], b1 = sW[tx * 4 + 1][k];
            float b2 = sW[tx * 4 + 2][k], b3 = sW[tx * 4 + 3][k];
            acc[0][0] += a0 * b0; acc[0][1] += a0 * b1; acc[0][2] += a0 * b2; acc[0][3] += a0 * b3;
            acc[1][0] += a1 * b0; acc[1][1] += a1 * b1; acc[1][2] += a1 * b2; acc[1][3] += a1 * b3;
            acc[2][0] += a2 * b0; acc[2][1] += a2 * b1; acc[2][2] += a2 * b2; acc[2][3] += a2 * b3;
            acc[3][0] += a3 * b0; acc[3][1] += a3 * b1; acc[3][2] += a3 * b2; acc[3][3] += a3 * b3;
        }
    }

#pragma unroll
    for (int ii = 0; ii < 4; ++ii) {
        int m = row0 + ty * 4 + ii;
        float dvm = dinv[m];
#pragma unroll
        for (int jj = 0; jj < 4; ++jj) {
            int n = col0 + tx * 4 + jj;
            float v = acc[ii][jj] + bias[n];
            v = fmaxf(v, 0.0f);
            size_t idx = (size_t)m * GD + n;
            if (h_out)  h_out[idx] = v;
            if (hs_out) {
                float s = skip ? skip[idx] : 0.0f;
                hs_out[idx] = dvm * (v + s);
            }
            if (sum_out) sum_out[idx] = v + add_src[idx];
        }
    }
}

// ---------------------------------------------------------------------------
extern "C" void kernel_launch(void* const* d_in, const int* in_sizes, int n_in,
                              void* d_out, int out_size, void* d_ws, size_t ws_size,
                              hipStream_t stream)
{
    const float* g  = (const float*)d_in[0];
    const float* h  = (const float*)d_in[1];
    const float* Wd = (const float*)d_in[2];
    const float* bd = (const float*)d_in[3];
    const float* Wb = (const float*)d_in[4];
    const float* bb = (const float*)d_in[5];
    const float* Wu = (const float*)d_in[6];
    const float* bu = (const float*)d_in[7];
    float* out = (float*)d_out;

    char* ws = (char*)d_ws;
    float*          dinv = (float*)ws;                               // 32 KB
    int*            cnt  = (int*)(ws + 32 * 1024);                   // 32 KB
    unsigned short* col  = (unsigned short*)(ws + 64 * 1024);        // 8192*CAP*2 = 5.24 MB
    size_t off = 64 * 1024 + (size_t)GN * CAP * sizeof(unsigned short);
    float* hs    = (float*)(ws + off);            // 8 MB
    float* yb    = hs + (size_t)GN * GD;          // 8 MB
    float* dbuf1 = yb + (size_t)GN * GD;          // 8 MB  (down_outs[0])
    float* dbuf2 = dbuf1 + (size_t)GN * GD;       // 8 MB  (down_outs[1])
    float* dbuf3 = dbuf2 + (size_t)GN * GD;       // 8 MB  (down_outs[2])
    (void)ws_size; (void)in_sizes; (void)n_in; (void)out_size;

    const size_t ND = (size_t)GN * GD;
    dim3 ggrid(GN / 64, GD / 64);
    dim3 sgrid(GN / 4, 4);

    k_build<<<GN, 256, 0, stream>>>(g, col, cnt, dinv);
    k_scale<<<GN * GD / 4 / 256, 256, 0, stream>>>(h, dinv, hs);

    // down 0..2: h_out -> dbuf, hs_out = dinv*h_next
    k_spmm<<<sgrid, 256, 0, stream>>>(hs, col, cnt, dinv, yb);
    k_gemm<<<ggrid, 256, 0, stream>>>(yb, Wd + 0 * GD * GD, bd + 0 * GD, dinv, nullptr, dbuf1, hs, nullptr, nullptr);
    k_spmm<<<sgrid, 256, 0, stream>>>(hs, col, cnt, dinv, yb);
    k_gemm<<<ggrid, 256, 0, stream>>>(yb, Wd + 1 * GD * GD, bd + 1 * GD, dinv, nullptr, dbuf2, hs, nullptr, nullptr);
    k_spmm<<<sgrid, 256, 0, stream>>>(hs, col, cnt, dinv, yb);
    k_gemm<<<ggrid, 256, 0, stream>>>(yb, Wd + 2 * GD * GD, bd + 2 * GD, dinv, nullptr, dbuf3, hs, nullptr, nullptr);

    // bottom: feeds next hs with skip = down_outs[2]
    k_spmm<<<sgrid, 256, 0, stream>>>(hs, col, cnt, dinv, yb);
    k_gemm<<<ggrid, 256, 0, stream>>>(yb, Wb, bb, dinv, dbuf3, nullptr, hs, nullptr, nullptr);

    // up 0: out[0] = h5; next hs = dinv*(h5 + down_outs[1])
    k_spmm<<<sgrid, 256, 0, stream>>>(hs, col, cnt, dinv, yb);
    k_gemm<<<ggrid, 256, 0, stream>>>(yb, Wu + 0 * GD * GD, bu + 0 * GD, dinv, dbuf2, out + 0 * ND, hs, nullptr, nullptr);
    // up 1: out[1] = h6; next hs = dinv*(h6 + down_outs[0])
    k_spmm<<<sgrid, 256, 0, stream>>>(hs, col, cnt, dinv, yb);
    k_gemm<<<ggrid, 256, 0, stream>>>(yb, Wu + 1 * GD * GD, bu + 1 * GD, dinv, dbuf1, out + 1 * ND, hs, nullptr, nullptr);
    // up 2: out[2] = h7; out[3] = h7 + org_h
    k_spmm<<<sgrid, 256, 0, stream>>>(hs, col, cnt, dinv, yb);
    k_gemm<<<ggrid, 256, 0, stream>>>(yb, Wu + 2 * GD * GD, bu + 2 * GD, dinv, nullptr, out + 2 * ND, nullptr, out + 3 * ND, h);
}

// Round 3
// 909.422 us; speedup vs baseline: 1.2621x; 1.0189x over previous
//
#include <hip/hip_runtime.h>
#include <cstdint>
#include <cstddef>

// Graph U-Net (no pooling), N=8192, D=256, L=3.
// g is ~1.5% dense after symmetrization (~127 avg degree). Build a
// fixed-stride ushort adjacency list once, then 7x (SpMM gather + fused GEMM).
// R3: float4 SpMM gathers, 4 neighbors in parallel per wave (16 lanes x
// float4 = 64-col chunk). 4x fewer gather/LDS/addr instructions; keeps the
// 2 MB per-chunk L2-resident footprint from R2.

#define GN 8192
#define GD 256
#define CAP 320   // max degree capacity; Binomial(8191, .0155) max ~175, 320 is safe

// ---------------------------------------------------------------------------
// Kernel 1: build adjacency lists + dinv. One block per row.
__global__ __launch_bounds__(256) void k_build(const float* __restrict__ g,
                                               unsigned short* __restrict__ col,
                                               int* __restrict__ cnt,
                                               float* __restrict__ dinv)
{
    __shared__ int s_cnt;
    const int i = blockIdx.x;
    const int tid = threadIdx.x;
    if (tid == 0) s_cnt = 0;
    __syncthreads();
    const float4* grow = (const float4*)(g + (size_t)i * GN);
    unsigned short* crow = col + (size_t)i * CAP;
    for (int j4 = tid; j4 < GN / 4; j4 += 256) {
        float4 v = grow[j4];
        int j = j4 * 4;
        if (v.x != 0.0f) { int p = atomicAdd(&s_cnt, 1); if (p < CAP) crow[p] = (unsigned short)(j + 0); }
        if (v.y != 0.0f) { int p = atomicAdd(&s_cnt, 1); if (p < CAP) crow[p] = (unsigned short)(j + 1); }
        if (v.z != 0.0f) { int p = atomicAdd(&s_cnt, 1); if (p < CAP) crow[p] = (unsigned short)(j + 2); }
        if (v.w != 0.0f) { int p = atomicAdd(&s_cnt, 1); if (p < CAP) crow[p] = (unsigned short)(j + 3); }
    }
    __syncthreads();
    if (tid == 0) {
        int n = s_cnt; if (n > CAP) n = CAP;
        cnt[i] = n;
        dinv[i] = rsqrtf((float)s_cnt + 1.0f);
    }
}

// ---------------------------------------------------------------------------
// Kernel 2: hs = dinv[:,None] * h   (initial pre-scale)
__global__ __launch_bounds__(256) void k_scale(const float* __restrict__ h,
                                               const float* __restrict__ dinv,
                                               float* __restrict__ hs)
{
    int idx = blockIdx.x * 256 + threadIdx.x;      // float4 index
    float4 v = ((const float4*)h)[idx];
    int row = idx / (GD / 4);
    float dv = dinv[row];
    v.x *= dv; v.y *= dv; v.z *= dv; v.w *= dv;
    ((float4*)hs)[idx] = v;
}

// ---------------------------------------------------------------------------
// Kernel 3: SpMM, float4 gathers. y[i, chunk] = dinv[i]*(hs[i,chunk] + sum_n hs[n,chunk])
// Grid (GN/4, 4): 4 rows/block (one wave each), one 64-col chunk per blockIdx.y.
// Wave layout: lane = j*16 + q. q indexes the 16 float4s of the chunk;
// j = 4 neighbor-parallel groups (neighbor t stride 4). Cross-group combine
// via shfl_xor(16), shfl_xor(32). No barriers (wave-coherent LDS staging).
__global__ __launch_bounds__(256) void k_spmm(const float* __restrict__ hs,
                                              const unsigned short* __restrict__ col,
                                              const int* __restrict__ cnt,
                                              const float* __restrict__ dinv,
                                              float* __restrict__ y)
{
    __shared__ unsigned short s_cols[4][CAP];
    const int tid = threadIdx.x;
    const int lr = tid >> 6;          // wave id = local row 0..3
    const int lane = tid & 63;
    const int j = lane >> 4;          // neighbor subset 0..3
    const int q = lane & 15;          // float4 index within 64-col chunk
    const int i = blockIdx.x * 4 + lr;
    const int n = cnt[i];
    unsigned short* sc = s_cols[lr];
    for (int t = lane; t < n; t += 64) sc[t] = col[(size_t)i * CAP + t];
    // wave-coherent: producer and consumer are the same wave; no barrier.

    const float4* hs4 = (const float4*)hs;
    const int cbase = blockIdx.y * 16 + q;    // float4 column index (row stride 64)

    float4 a0 = {0.f,0.f,0.f,0.f}, a1 = {0.f,0.f,0.f,0.f};
    float4 a2 = {0.f,0.f,0.f,0.f}, a3 = {0.f,0.f,0.f,0.f};
    int t = j;
    for (; t + 12 < n; t += 16) {
        int c0 = sc[t], c1 = sc[t + 4], c2 = sc[t + 8], c3 = sc[t + 12];
        float4 v0 = hs4[(size_t)c0 * 64 + cbase];
        float4 v1 = hs4[(size_t)c1 * 64 + cbase];
        float4 v2 = hs4[(size_t)c2 * 64 + cbase];
        float4 v3 = hs4[(size_t)c3 * 64 + cbase];
        a0.x += v0.x; a0.y += v0.y; a0.z += v0.z; a0.w += v0.w;
        a1.x += v1.x; a1.y += v1.y; a1.z += v1.z; a1.w += v1.w;
        a2.x += v2.x; a2.y += v2.y; a2.z += v2.z; a2.w += v2.w;
        a3.x += v3.x; a3.y += v3.y; a3.z += v3.z; a3.w += v3.w;
    }
    for (; t < n; t += 4) {
        float4 v0 = hs4[(size_t)sc[t] * 64 + cbase];
        a0.x += v0.x; a0.y += v0.y; a0.z += v0.z; a0.w += v0.w;
    }
    float4 acc;
    acc.x = (a0.x + a1.x) + (a2.x + a3.x);
    acc.y = (a0.y + a1.y) + (a2.y + a3.y);
    acc.z = (a0.z + a1.z) + (a2.z + a3.z);
    acc.w = (a0.w + a1.w) + (a2.w + a3.w);

    // combine the 4 neighbor subsets (lanes ^16, ^32)
    acc.x += __shfl_xor(acc.x, 16, 64);
    acc.y += __shfl_xor(acc.y, 16, 64);
    acc.z += __shfl_xor(acc.z, 16, 64);
    acc.w += __shfl_xor(acc.w, 16, 64);
    acc.x += __shfl_xor(acc.x, 32, 64);
    acc.y += __shfl_xor(acc.y, 32, 64);
    acc.z += __shfl_xor(acc.z, 32, 64);
    acc.w += __shfl_xor(acc.w, 32, 64);

    if (j == 0) {
        float4 self = hs4[(size_t)i * 64 + cbase];
        float dv = dinv[i];
        float4 r;
        r.x = dv * (acc.x + self.x);
        r.y = dv * (acc.y + self.y);
        r.z = dv * (acc.z + self.z);
        r.w = dv * (acc.w + self.w);
        ((float4*)y)[(size_t)i * 64 + cbase] = r;
    }
}

// ---------------------------------------------------------------------------
// Kernel 4: fused linear layer.  out = relu(Y @ W^T + b), plus epilogues:
//   h_out[idx]  = v                         (store layer output if needed)
//   hs_out[idx] = dinv[m] * (v + skip[idx]) (pre-scaled input for next SpMM)
//   sum_out[idx]= v + add_src[idx]          (final h + org_h output)
__global__ __launch_bounds__(256) void k_gemm(const float* __restrict__ Y,
                                              const float* __restrict__ W,
                                              const float* __restrict__ bias,
                                              const float* __restrict__ dinv,
                                              const float* __restrict__ skip,
                                              float* __restrict__ h_out,
                                              float* __restrict__ hs_out,
                                              float* __restrict__ sum_out,
                                              const float* __restrict__ add_src)
{
    const int BM = 64, BN = 64, BK = 32;
    __shared__ float sY[BM][BK + 1];
    __shared__ float sW[BN][BK + 1];
    const int by = blockIdx.x;   // 0..127 row tiles
    const int bx = blockIdx.y;   // 0..3   col tiles
    const int tid = threadIdx.x;
    const int tx = tid & 15, ty = tid >> 4;
    const int row0 = by * BM, col0 = bx * BN;
    const int lrow = tid >> 3;        // 0..31
    const int lk = (tid & 7) * 4;     // 0,4,...,28

    float acc[4][4] = {};

    for (int k0 = 0; k0 < GD; k0 += BK) {
        float4 ya = *(const float4*)&Y[(size_t)(row0 + lrow) * GD + k0 + lk];
        float4 yb = *(const float4*)&Y[(size_t)(row0 + lrow + 32) * GD + k0 + lk];
        float4 wa = *(const float4*)&W[(size_t)(col0 + lrow) * GD + k0 + lk];
        float4 wb = *(const float4*)&W[(size_t)(col0 + lrow + 32) * GD + k0 + lk];
        __syncthreads();
        sY[lrow][lk + 0] = ya.x; sY[lrow][lk + 1] = ya.y; sY[lrow][lk + 2] = ya.z; sY[lrow][lk + 3] = ya.w;
        sY[lrow + 32][lk + 0] = yb.x; sY[lrow + 32][lk + 1] = yb.y; sY[lrow + 32][lk + 2] = yb.z; sY[lrow + 32][lk + 3] = yb.w;
        sW[lrow][lk + 0] = wa.x; sW[lrow][lk + 1] = wa.y; sW[lrow][lk + 2] = wa.z; sW[lrow][lk + 3] = wa.w;
        sW[lrow + 32][lk + 0] = wb.x; sW[lrow + 32][lk + 1] = wb.y; sW[lrow + 32][lk + 2] = wb.z; sW[lrow + 32][lk + 3] = wb.w;
        __syncthreads();
#pragma unroll
        for (int k = 0; k < BK; ++k) {
            float a0 = sY[ty * 4 + 0][k], a1 = sY[ty * 4 + 1][k];
            float a2 = sY[ty * 4 + 2][k], a3 = sY[ty * 4 + 3][k];
            float b0 = sW[tx * 4 + 0][k], b1 = sW[tx * 4 + 1][k];
            float b2 = sW[tx * 4 + 2][k], b3 = sW[tx * 4 + 3][k];
            acc[0][0] += a0 * b0; acc[0][1] += a0 * b1; acc[0][2] += a0 * b2; acc[0][3] += a0 * b3;
            acc[1][0] += a1 * b0; acc[1][1] += a1 * b1; acc[1][2] += a1 * b2; acc[1][3] += a1 * b3;
            acc[2][0] += a2 * b0; acc[2][1] += a2 * b1; acc[2][2] += a2 * b2; acc[2][3] += a2 * b3;
            acc[3][0] += a3 * b0; acc[3][1] += a3 * b1; acc[3][2] += a3 * b2; acc[3][3] += a3 * b3;
        }
    }

#pragma unroll
    for (int ii = 0; ii < 4; ++ii) {
        int m = row0 + ty * 4 + ii;
        float dvm = dinv[m];
#pragma unroll
        for (int jj = 0; jj < 4; ++jj) {
            int n = col0 + tx * 4 + jj;
            float v = acc[ii][jj] + bias[n];
            v = fmaxf(v, 0.0f);
            size_t idx = (size_t)m * GD + n;
            if (h_out)  h_out[idx] = v;
            if (hs_out) {
                float s = skip ? skip[idx] : 0.0f;
                hs_out[idx] = dvm * (v + s);
            }
            if (sum_out) sum_out[idx] = v + add_src[idx];
        }
    }
}

// ---------------------------------------------------------------------------
extern "C" void kernel_launch(void* const* d_in, const int* in_sizes, int n_in,
                              void* d_out, int out_size, void* d_ws, size_t ws_size,
                              hipStream_t stream)
{
    const float* g  = (const float*)d_in[0];
    const float* h  = (const float*)d_in[1];
    const float* Wd = (const float*)d_in[2];
    const float* bd = (const float*)d_in[3];
    const float* Wb = (const float*)d_in[4];
    const float* bb = (const float*)d_in[5];
    const float* Wu = (const float*)d_in[6];
    const float* bu = (const float*)d_in[7];
    float* out = (float*)d_out;

    char* ws = (char*)d_ws;
    float*          dinv = (float*)ws;                               // 32 KB
    int*            cnt  = (int*)(ws + 32 * 1024);                   // 32 KB
    unsigned short* col  = (unsigned short*)(ws + 64 * 1024);        // 8192*CAP*2 = 5.24 MB
    size_t off = 64 * 1024 + (size_t)GN * CAP * sizeof(unsigned short);
    float* hs    = (float*)(ws + off);            // 8 MB
    float* yb    = hs + (size_t)GN * GD;          // 8 MB
    float* dbuf1 = yb + (size_t)GN * GD;          // 8 MB  (down_outs[0])
    float* dbuf2 = dbuf1 + (size_t)GN * GD;       // 8 MB  (down_outs[1])
    float* dbuf3 = dbuf2 + (size_t)GN * GD;       // 8 MB  (down_outs[2])
    (void)ws_size; (void)in_sizes; (void)n_in; (void)out_size;

    const size_t ND = (size_t)GN * GD;
    dim3 ggrid(GN / 64, GD / 64);
    dim3 sgrid(GN / 4, 4);

    k_build<<<GN, 256, 0, stream>>>(g, col, cnt, dinv);
    k_scale<<<GN * GD / 4 / 256, 256, 0, stream>>>(h, dinv, hs);

    // down 0..2: h_out -> dbuf, hs_out = dinv*h_next
    k_spmm<<<sgrid, 256, 0, stream>>>(hs, col, cnt, dinv, yb);
    k_gemm<<<ggrid, 256, 0, stream>>>(yb, Wd + 0 * GD * GD, bd + 0 * GD, dinv, nullptr, dbuf1, hs, nullptr, nullptr);
    k_spmm<<<sgrid, 256, 0, stream>>>(hs, col, cnt, dinv, yb);
    k_gemm<<<ggrid, 256, 0, stream>>>(yb, Wd + 1 * GD * GD, bd + 1 * GD, dinv, nullptr, dbuf2, hs, nullptr, nullptr);
    k_spmm<<<sgrid, 256, 0, stream>>>(hs, col, cnt, dinv, yb);
    k_gemm<<<ggrid, 256, 0, stream>>>(yb, Wd + 2 * GD * GD, bd + 2 * GD, dinv, nullptr, dbuf3, hs, nullptr, nullptr);

    // bottom: feeds next hs with skip = down_outs[2]
    k_spmm<<<sgrid, 256, 0, stream>>>(hs, col, cnt, dinv, yb);
    k_gemm<<<ggrid, 256, 0, stream>>>(yb, Wb, bb, dinv, dbuf3, nullptr, hs, nullptr, nullptr);

    // up 0: out[0] = h5; next hs = dinv*(h5 + down_outs[1])
    k_spmm<<<sgrid, 256, 0, stream>>>(hs, col, cnt, dinv, yb);
    k_gemm<<<ggrid, 256, 0, stream>>>(yb, Wu + 0 * GD * GD, bu + 0 * GD, dinv, dbuf2, out + 0 * ND, hs, nullptr, nullptr);
    // up 1: out[1] = h6; next hs = dinv*(h6 + down_outs[0])
    k_spmm<<<sgrid, 256, 0, stream>>>(hs, col, cnt, dinv, yb);
    k_gemm<<<ggrid, 256, 0, stream>>>(yb, Wu + 1 * GD * GD, bu + 1 * GD, dinv, dbuf1, out + 1 * ND, hs, nullptr, nullptr);
    // up 2: out[2] = h7; out[3] = h7 + org_h
    k_spmm<<<sgrid, 256, 0, stream>>>(hs, col, cnt, dinv, yb);
    k_gemm<<<ggrid, 256, 0, stream>>>(yb, Wu + 2 * GD * GD, bu + 2 * GD, dinv, nullptr, out + 2 * ND, nullptr, out + 3 * ND, h);
}

// Round 4
// 699.117 us; speedup vs baseline: 1.6417x; 1.3008x over previous
//
#include <hip/hip_runtime.h>
#include <cstdint>
#include <cstddef>

// Graph U-Net (no pooling), N=8192, D=256, L=3.
// R4: (1) GEMM -> MFMA bf16 16x16x32, fragments direct from global (no LDS);
//     (2) SpMM gathers in bf16 (hs stored prescaled bf16, 4 MB; 128-col
//         chunks -> 2 MB L2-resident footprint), fp32 accumulate;
//     (3) all epilogues fp32 (MFMA acc is fp32), skips fp32.

#define GN 8192
#define GD 256
#define CAP 320   // max degree capacity; max observed degree ~175

typedef unsigned int uint32;
using frag_ab = __attribute__((ext_vector_type(8))) short;   // 8 bf16
using frag_cd = __attribute__((ext_vector_type(4))) float;   // 4 fp32

// RNE float -> bf16 bits (values are finite; NaN path not needed)
static __device__ inline unsigned short f2bf(float x) {
    uint32 u = __float_as_uint(x);
    u += 0x7fffu + ((u >> 16) & 1u);
    return (unsigned short)(u >> 16);
}

// ---------------------------------------------------------------------------
// Kernel 1: build adjacency lists + dinv. One block per row. (unchanged)
__global__ __launch_bounds__(256) void k_build(const float* __restrict__ g,
                                               unsigned short* __restrict__ col,
                                               int* __restrict__ cnt,
                                               float* __restrict__ dinv)
{
    __shared__ int s_cnt;
    const int i = blockIdx.x;
    const int tid = threadIdx.x;
    if (tid == 0) s_cnt = 0;
    __syncthreads();
    const float4* grow = (const float4*)(g + (size_t)i * GN);
    unsigned short* crow = col + (size_t)i * CAP;
    for (int j4 = tid; j4 < GN / 4; j4 += 256) {
        float4 v = grow[j4];
        int j = j4 * 4;
        if (v.x != 0.0f) { int p = atomicAdd(&s_cnt, 1); if (p < CAP) crow[p] = (unsigned short)(j + 0); }
        if (v.y != 0.0f) { int p = atomicAdd(&s_cnt, 1); if (p < CAP) crow[p] = (unsigned short)(j + 1); }
        if (v.z != 0.0f) { int p = atomicAdd(&s_cnt, 1); if (p < CAP) crow[p] = (unsigned short)(j + 2); }
        if (v.w != 0.0f) { int p = atomicAdd(&s_cnt, 1); if (p < CAP) crow[p] = (unsigned short)(j + 3); }
    }
    __syncthreads();
    if (tid == 0) {
        int n = s_cnt; if (n > CAP) n = CAP;
        cnt[i] = n;
        dinv[i] = rsqrtf((float)s_cnt + 1.0f);
    }
}

// ---------------------------------------------------------------------------
// Kernel 2: hs_bf = bf16(dinv[:,None] * h)
__global__ __launch_bounds__(256) void k_scale(const float* __restrict__ h,
                                               const float* __restrict__ dinv,
                                               unsigned short* __restrict__ hs_bf)
{
    int idx = blockIdx.x * 256 + threadIdx.x;      // float4 index
    float4 v = ((const float4*)h)[idx];
    int row = idx / (GD / 4);
    float dv = dinv[row];
    ushort4 r;
    r.x = f2bf(v.x * dv); r.y = f2bf(v.y * dv);
    r.z = f2bf(v.z * dv); r.w = f2bf(v.w * dv);
    ((ushort4*)hs_bf)[idx] = r;
}

// ---------------------------------------------------------------------------
// Kernel 2b: generic fp32 -> bf16 convert (weights), n multiple of 1024
__global__ __launch_bounds__(256) void k_f2bf(const float* __restrict__ src,
                                              unsigned short* __restrict__ dst)
{
    int idx = blockIdx.x * 256 + threadIdx.x;      // float4 index
    float4 v = ((const float4*)src)[idx];
    ushort4 r;
    r.x = f2bf(v.x); r.y = f2bf(v.y); r.z = f2bf(v.z); r.w = f2bf(v.w);
    ((ushort4*)dst)[idx] = r;
}

// ---------------------------------------------------------------------------
// Kernel 3: SpMM, bf16 gathers. y_bf[i,:] = bf16(dinv[i]*(hs[i,:] + sum_n hs[n,:]))
// Grid (GN/4, 2): 4 rows/block (one wave each), 128-col chunk per blockIdx.y.
// Lane owns one uint (2 bf16). Per neighbor: 1 dword gather (wave = 256 B
// contiguous), shl/and unpack, 2 fp32 adds. Footprint/chunk = 2 MB.
__global__ __launch_bounds__(256) void k_spmm(const uint32* __restrict__ hsw,
                                              const unsigned short* __restrict__ col,
                                              const int* __restrict__ cnt,
                                              const float* __restrict__ dinv,
                                              uint32* __restrict__ yw)
{
    __shared__ unsigned short s_cols[4][CAP];
    const int tid = threadIdx.x;
    const int lr = tid >> 6;          // wave id = local row 0..3
    const int lane = tid & 63;
    const int i = blockIdx.x * 4 + lr;
    const int base = blockIdx.y * 64 + lane;   // uint col index (row stride 128)
    const int n = cnt[i];
    unsigned short* sc = s_cols[lr];
    for (int t = lane; t < n; t += 64) sc[t] = col[(size_t)i * CAP + t];
    // wave-coherent staging: producer == consumer wave; no barrier.

    float alo = 0.f, ahi = 0.f;
    int t = 0;
    for (; t + 4 <= n; t += 4) {
        int c0 = sc[t], c1 = sc[t + 1], c2 = sc[t + 2], c3 = sc[t + 3];
        uint32 u0 = hsw[(size_t)c0 * 128 + base];
        uint32 u1 = hsw[(size_t)c1 * 128 + base];
        uint32 u2 = hsw[(size_t)c2 * 128 + base];
        uint32 u3 = hsw[(size_t)c3 * 128 + base];
        alo += __uint_as_float(u0 << 16); ahi += __uint_as_float(u0 & 0xffff0000u);
        alo += __uint_as_float(u1 << 16); ahi += __uint_as_float(u1 & 0xffff0000u);
        alo += __uint_as_float(u2 << 16); ahi += __uint_as_float(u2 & 0xffff0000u);
        alo += __uint_as_float(u3 << 16); ahi += __uint_as_float(u3 & 0xffff0000u);
    }
    for (; t < n; ++t) {
        uint32 u = hsw[(size_t)sc[t] * 128 + base];
        alo += __uint_as_float(u << 16); ahi += __uint_as_float(u & 0xffff0000u);
    }
    uint32 us = hsw[(size_t)i * 128 + base];   // self-loop (+I)
    alo += __uint_as_float(us << 16); ahi += __uint_as_float(us & 0xffff0000u);
    float dv = dinv[i];
    alo *= dv; ahi *= dv;
    yw[(size_t)i * 128 + base] = (uint32)f2bf(alo) | ((uint32)f2bf(ahi) << 16);
}

// ---------------------------------------------------------------------------
// Kernel 4: MFMA bf16 linear layer. C = relu(Y @ W^T + b) with epilogues:
//   h_out  (fp32) : layer output (skip storage / final out slots)
//   hs_out (bf16) : bf16(dinv[m]*(v + skip)) — next SpMM input
//   sum_out(fp32) : v + add_src (final h7 + org_h)
// Y [8192][256] bf16 row-major; W [256][256] bf16 row-major ([out][in] -> B^T,
// K contiguous). Fragments loaded directly from global (16 B per lane), no LDS.
// Layouts (m89/m91-verified): A[m=lane&15][k=quad*8+j]; C/D row=quad*4+reg,
// col=lane&15.
__global__ __launch_bounds__(256) void k_gemm(const unsigned short* __restrict__ Y,
                                              const unsigned short* __restrict__ W,
                                              const float* __restrict__ bias,
                                              const float* __restrict__ dinv,
                                              const float* __restrict__ skip,
                                              float* __restrict__ h_out,
                                              unsigned short* __restrict__ hs_out,
                                              float* __restrict__ sum_out,
                                              const float* __restrict__ add_src)
{
    const int tid  = threadIdx.x;
    const int w    = tid >> 6;         // wave 0..3
    const int lane = tid & 63;
    const int quad = lane >> 4;
    const int l16  = lane & 15;
    const int m0 = blockIdx.x * 64 + w * 16;   // wave's 16 rows
    const int n0 = blockIdx.y * 64;            // block's 64 cols

    frag_cd acc0 = {0.f,0.f,0.f,0.f}, acc1 = {0.f,0.f,0.f,0.f};
    frag_cd acc2 = {0.f,0.f,0.f,0.f}, acc3 = {0.f,0.f,0.f,0.f};

    const size_t abase  = (size_t)(m0 + l16) * GD + quad * 8;
    const size_t bbase0 = (size_t)(n0 +  0 + l16) * GD + quad * 8;
    const size_t bbase1 = (size_t)(n0 + 16 + l16) * GD + quad * 8;
    const size_t bbase2 = (size_t)(n0 + 32 + l16) * GD + quad * 8;
    const size_t bbase3 = (size_t)(n0 + 48 + l16) * GD + quad * 8;

#pragma unroll
    for (int k0 = 0; k0 < GD; k0 += 32) {
        frag_ab a  = *(const frag_ab*)(Y + abase  + k0);
        frag_ab b0 = *(const frag_ab*)(W + bbase0 + k0);
        frag_ab b1 = *(const frag_ab*)(W + bbase1 + k0);
        frag_ab b2 = *(const frag_ab*)(W + bbase2 + k0);
        frag_ab b3 = *(const frag_ab*)(W + bbase3 + k0);
        acc0 = __builtin_amdgcn_mfma_f32_16x16x32_bf16(a, b0, acc0, 0, 0, 0);
        acc1 = __builtin_amdgcn_mfma_f32_16x16x32_bf16(a, b1, acc1, 0, 0, 0);
        acc2 = __builtin_amdgcn_mfma_f32_16x16x32_bf16(a, b2, acc2, 0, 0, 0);
        acc3 = __builtin_amdgcn_mfma_f32_16x16x32_bf16(a, b3, acc3, 0, 0, 0);
    }

    const float bn0 = bias[n0 +  0 + l16];
    const float bn1 = bias[n0 + 16 + l16];
    const float bn2 = bias[n0 + 32 + l16];
    const float bn3 = bias[n0 + 48 + l16];

#pragma unroll
    for (int reg = 0; reg < 4; ++reg) {
        const int m = m0 + quad * 4 + reg;
        const float dv = dinv[m];
        const size_t rbase = (size_t)m * GD + l16;
        float v[4];
        v[0] = fmaxf(acc0[reg] + bn0, 0.f);
        v[1] = fmaxf(acc1[reg] + bn1, 0.f);
        v[2] = fmaxf(acc2[reg] + bn2, 0.f);
        v[3] = fmaxf(acc3[reg] + bn3, 0.f);
#pragma unroll
        for (int nt = 0; nt < 4; ++nt) {
            const size_t idx = rbase + n0 * 0 + nt * 16 + n0; // (expanded below)
        }
        // expanded stores (avoid fake loop above being used — do it directly):
#pragma unroll
        for (int nt = 0; nt < 4; ++nt) {
            const size_t idx = (size_t)m * GD + n0 + nt * 16 + l16;
            const float x = v[nt];
            if (h_out)  h_out[idx] = x;
            if (hs_out) {
                float s = skip ? skip[idx] : 0.f;
                hs_out[idx] = f2bf(dv * (x + s));
            }
            if (sum_out) sum_out[idx] = x + add_src[idx];
        }
    }
}

// ---------------------------------------------------------------------------
extern "C" void kernel_launch(void* const* d_in, const int* in_sizes, int n_in,
                              void* d_out, int out_size, void* d_ws, size_t ws_size,
                              hipStream_t stream)
{
    const float* g  = (const float*)d_in[0];
    const float* h  = (const float*)d_in[1];
    const float* Wd = (const float*)d_in[2];
    const float* bd = (const float*)d_in[3];
    const float* Wb = (const float*)d_in[4];
    const float* bb = (const float*)d_in[5];
    const float* Wu = (const float*)d_in[6];
    const float* bu = (const float*)d_in[7];
    float* out = (float*)d_out;

    char* ws = (char*)d_ws;
    float*          dinv = (float*)ws;                               // 32 KB
    int*            cnt  = (int*)(ws + 32 * 1024);                   // 32 KB
    unsigned short* col  = (unsigned short*)(ws + 64 * 1024);        // 5.24 MB
    size_t off = 64 * 1024 + (size_t)GN * CAP * sizeof(unsigned short);
    off = (off + 255) & ~(size_t)255;
    unsigned short* hs_bf = (unsigned short*)(ws + off); off += (size_t)GN * GD * 2;  // 4 MB
    unsigned short* y_bf  = (unsigned short*)(ws + off); off += (size_t)GN * GD * 2;  // 4 MB
    unsigned short* w_bf  = (unsigned short*)(ws + off); off += (size_t)7 * GD * GD * 2; // 0.9 MB
    off = (off + 255) & ~(size_t)255;
    float* dbuf1 = (float*)(ws + off); off += (size_t)GN * GD * 4;   // 8 MB
    float* dbuf2 = (float*)(ws + off); off += (size_t)GN * GD * 4;   // 8 MB
    float* dbuf3 = (float*)(ws + off); off += (size_t)GN * GD * 4;   // 8 MB
    (void)ws_size; (void)in_sizes; (void)n_in; (void)out_size;

    const size_t ND = (size_t)GN * GD;
    const int WSZ = GD * GD;   // 65536 elements per weight matrix
    dim3 ggrid(GN / 64, GD / 64);
    dim3 sgrid(GN / 4, 2);

    k_build<<<GN, 256, 0, stream>>>(g, col, cnt, dinv);
    k_scale<<<GN * GD / 4 / 256, 256, 0, stream>>>(h, dinv, hs_bf);
    k_f2bf<<<3 * WSZ / 4 / 256, 256, 0, stream>>>(Wd, w_bf + 0 * (size_t)WSZ);
    k_f2bf<<<1 * WSZ / 4 / 256, 256, 0, stream>>>(Wb, w_bf + 3 * (size_t)WSZ);
    k_f2bf<<<3 * WSZ / 4 / 256, 256, 0, stream>>>(Wu, w_bf + 4 * (size_t)WSZ);

    // down 0..2: h_out -> dbuf, hs_out -> hs_bf (no skip)
    k_spmm<<<sgrid, 256, 0, stream>>>((const uint32*)hs_bf, col, cnt, dinv, (uint32*)y_bf);
    k_gemm<<<ggrid, 256, 0, stream>>>(y_bf, w_bf + 0 * (size_t)WSZ, bd + 0 * GD, dinv, nullptr, dbuf1, hs_bf, nullptr, nullptr);
    k_spmm<<<sgrid, 256, 0, stream>>>((const uint32*)hs_bf, col, cnt, dinv, (uint32*)y_bf);
    k_gemm<<<ggrid, 256, 0, stream>>>(y_bf, w_bf + 1 * (size_t)WSZ, bd + 1 * GD, dinv, nullptr, dbuf2, hs_bf, nullptr, nullptr);
    k_spmm<<<sgrid, 256, 0, stream>>>((const uint32*)hs_bf, col, cnt, dinv, (uint32*)y_bf);
    k_gemm<<<ggrid, 256, 0, stream>>>(y_bf, w_bf + 2 * (size_t)WSZ, bd + 2 * GD, dinv, nullptr, dbuf3, hs_bf, nullptr, nullptr);

    // bottom: hs_out with skip = down_outs[2]
    k_spmm<<<sgrid, 256, 0, stream>>>((const uint32*)hs_bf, col, cnt, dinv, (uint32*)y_bf);
    k_gemm<<<ggrid, 256, 0, stream>>>(y_bf, w_bf + 3 * (size_t)WSZ, bb, dinv, dbuf3, nullptr, hs_bf, nullptr, nullptr);

    // up 0: out[0] = h5; next hs with skip = down_outs[1]
    k_spmm<<<sgrid, 256, 0, stream>>>((const uint32*)hs_bf, col, cnt, dinv, (uint32*)y_bf);
    k_gemm<<<ggrid, 256, 0, stream>>>(y_bf, w_bf + 4 * (size_t)WSZ, bu + 0 * GD, dinv, dbuf2, out + 0 * ND, hs_bf, nullptr, nullptr);
    // up 1: out[1] = h6; next hs with skip = down_outs[0]
    k_spmm<<<sgrid, 256, 0, stream>>>((const uint32*)hs_bf, col, cnt, dinv, (uint32*)y_bf);
    k_gemm<<<ggrid, 256, 0, stream>>>(y_bf, w_bf + 5 * (size_t)WSZ, bu + 1 * GD, dinv, dbuf1, out + 1 * ND, hs_bf, nullptr, nullptr);
    // up 2: out[2] = h7; out[3] = h7 + org_h
    k_spmm<<<sgrid, 256, 0, stream>>>((const uint32*)hs_bf, col, cnt, dinv, (uint32*)y_bf);
    k_gemm<<<ggrid, 256, 0, stream>>>(y_bf, w_bf + 6 * (size_t)WSZ, bu + 2 * GD, dinv, nullptr, out + 2 * ND, nullptr, out + 3 * ND, h);
}